// Round 18
// baseline (29.225 us; speedup 1.0000x reference)
//
#include <hip/hip_runtime.h>
#include <hip/hip_bf16.h>

#define NB 16      // batch
#define TT 1024    // Tq == Tk
#define NH 4       // heads
#define HD 6       // head dim
#define DM 24      // model dim

// (1/sqrt(6)) * log2(e) -- folded into Q so scores are in exp2 domain
#define QSC 0.5889785f
// fixed conservative bias (log2 domain); softmax invariant; p <= 1, no overflow
#define MBIAS 32.0f

typedef float v2f __attribute__((ext_vector_type(2)));
typedef short bf16x8 __attribute__((ext_vector_type(8)));    // MFMA A/B frag
typedef float f32x16 __attribute__((ext_vector_type(16)));   // MFMA 32x32 C/D
typedef unsigned u32x2 __attribute__((ext_vector_type(2)));

__device__ __forceinline__ unsigned cvt_pk_bf16(float lo, float hi) {
  unsigned r;
  asm("v_cvt_pk_bf16_f32 %0, %1, %2" : "=v"(r) : "v"(lo), "v"(hi));
  return r;
}

__device__ __forceinline__ bf16x8 as_bf16x8(uint4 u) {
  union { uint4 u; bf16x8 b; } c;
  c.u = u;
  return c.b;
}

// packed dot of one 24-float row with a uniform (SGPR) weight row
__device__ __forceinline__ float dot24(const float4* r,
                                       const float* __restrict__ w) {
  v2f a = {0.f, 0.f};
#pragma unroll
  for (int i = 0; i < 6; ++i) {
    v2f xp, wp;
    xp.x = r[i].x; xp.y = r[i].y;
    wp.x = w[4 * i + 0]; wp.y = w[4 * i + 1];
    a = __builtin_elementwise_fma(xp, wp, a);
    xp.x = r[i].z; xp.y = r[i].w;
    wp.x = w[4 * i + 2]; wp.y = w[4 * i + 3];
    a = __builtin_elementwise_fma(xp, wp, a);
  }
  return a.x + a.y;
}

#define KSPLIT 2
#define KPB (TT / KSPLIT)  // 512 keys/block
#define QB 128             // queries/block
#define ITERS (KPB / 32)   // 16

// ---------- kernel 1: coalesced fine-grained K/V projection ----------
// R16-fixed: (i) no duplicate X_en loads (one thread per key for K);
// (ii) V written as u32 bf16-pairs, plane-major -> fully coalesced;
// (iii) grid 1024 blocks (4/CU), 2-6 short dot-chains per thread.
// Kg[(bh*2+ks)*512+loc]   = uint4 (k0..k5,0,0 bf16)  [16B coalesced store]
// Vt[((bh*2+ks)*6+d)*256+pair] = u32 (vA,vB bf16)    [4B coalesced store]
__global__ __launch_bounds__(256, 4) void kvproj_kernel(
    const float* __restrict__ Xen, const float* __restrict__ Wk,
    const float* __restrict__ Wv, uint4* __restrict__ Kg,
    unsigned* __restrict__ Vt) {
  const int gid = blockIdx.x * 256 + threadIdx.x;
  if (blockIdx.x < 256) {
    // ---- K section: one thread per key (6 dots, 16B store)
    const int bh = gid >> 10, key = gid & (TT - 1);
    const int b = bh >> 2, h = bh & 3;
    const int ks = key >> 9, loc = key & (KPB - 1);
    const float* __restrict__ wkh = Wk + h * HD * DM;
    const float4* __restrict__ xa =
        (const float4*)(Xen + ((size_t)b * TT + key) * DM);
    float4 xr[6];
#pragma unroll
    for (int i = 0; i < 6; ++i) xr[i] = xa[i];
    float kk[HD];
#pragma unroll
    for (int d = 0; d < HD; ++d) kk[d] = dot24(xr, wkh + d * DM);
    Kg[((size_t)(bh * KSPLIT + ks)) * KPB + loc] =
        make_uint4(cvt_pk_bf16(kk[0], kk[1]), cvt_pk_bf16(kk[2], kk[3]),
                   cvt_pk_bf16(kk[4], kk[5]), 0u);
  } else {
    // ---- V section: one thread per (plane=(bh,ks,d), key-pair) (2 dots)
    const int vg = gid - 256 * 256;     // [0, 768*256)
    const int plane = vg >> 8;          // (bh*2+ks)*6 + d
    const int pair = vg & 255;
    const int bhks = plane / 6;
    const int d = plane - 6 * bhks;
    const int bh = bhks >> 1, ks = bhks & 1;
    const int b = bh >> 2, h = bh & 3;
    const int key = ks * KPB + 2 * pair;
    const float* __restrict__ wvd = Wv + (h * HD + d) * DM;
    const float4* __restrict__ xa =
        (const float4*)(Xen + ((size_t)b * TT + key) * DM);
    float4 xr[12];
#pragma unroll
    for (int i = 0; i < 12; ++i) xr[i] = xa[i];
    const float vA = dot24(xr + 0, wvd);
    const float vB = dot24(xr + 6, wvd);
    Vt[(size_t)plane * 256 + pair] = cvt_pk_bf16(vA, vB);
  }
}

// ---------- kernel 2: staged 32x32 MFMA attention (R13 loop verbatim) ------
__global__ __launch_bounds__(256, 4) void fused_attn32_kernel(
    const float* __restrict__ X, const float* __restrict__ Wq,
    const uint4* __restrict__ Kg, const unsigned* __restrict__ Vt,
    float* __restrict__ P) {
  __shared__ __align__(16) uint4 Kl[KPB];       // 8192 B
  __shared__ __align__(16) unsigned Vl[7][264]; // 7392 B

  const int ks = blockIdx.x & 1;
  const int tile = (blockIdx.x >> 1) & 7;
  const int bh = blockIdx.x >> 4;
  const int b = bh >> 2, h = bh & 3;
  const int t = threadIdx.x;

  // ---- issue coalesced staging loads FIRST (latency hides under Q-proj)
  const uint4* __restrict__ Kgp = Kg + ((size_t)(bh * KSPLIT + ks)) * KPB;
  const unsigned* __restrict__ Vtp =
      Vt + ((size_t)(bh * KSPLIT + ks)) * (6 * 256);
  const uint4 k0 = Kgp[2 * t];
  const uint4 k1 = Kgp[2 * t + 1];
  unsigned vr[HD];
#pragma unroll
  for (int d = 0; d < HD; ++d) vr[d] = Vtp[d * 256 + t];

  // ---- Q projection -> B-frag (hi==0 lanes real, hi==1 zero)
  const int lane = t & 63;
  const int w = t >> 6;
  const int hi = lane >> 5;
  const int qc = lane & 31;
  const int q = tile * QB + w * 32 + qc;
  const float* __restrict__ wqh = Wq + h * HD * DM;
  uint4 uq = make_uint4(0u, 0u, 0u, 0u);
  if (hi == 0) {
    const float4* __restrict__ xq =
        (const float4*)(X + ((size_t)b * TT + q) * DM);
    float4 xr[6];
#pragma unroll
    for (int i = 0; i < 6; ++i) xr[i] = xq[i];
    float qv[HD];
#pragma unroll
    for (int d = 0; d < HD; ++d) qv[d] = dot24(xr, wqh + d * DM) * QSC;
    uq = make_uint4(cvt_pk_bf16(qv[0], qv[1]), cvt_pk_bf16(qv[2], qv[3]),
                    cvt_pk_bf16(qv[4], qv[5]), 0u);
  }
  const bf16x8 qfrag = as_bf16x8(uq);

  // ---- write staged K/V into LDS images
  Kl[2 * t] = k0;
  Kl[2 * t + 1] = k1;
#pragma unroll
  for (int d = 0; d < HD; ++d) Vl[d][t] = vr[d];
  Vl[6][t] = 0x3F803F80u;  // ones row -> l via MFMA row 6

  __syncthreads();  // LDS K/V ready

  f32x16 cmb, oacc;
#pragma unroll
  for (int i = 0; i < 16; ++i) { cmb[i] = -MBIAS; oacc[i] = 0.f; }

  const int dcl = (qc < 7) ? qc : 6;
  const uint4 zero4 = make_uint4(0u, 0u, 0u, 0u);

  // ---- main loop (R11/R13-proven, verbatim)
#pragma unroll 2
  for (int it = 0; it < ITERS; ++it) {
    const uint4 ka = (hi == 0) ? Kl[it * 32 + qc] : zero4;
    const uint4 vv = *(const uint4*)&Vl[dcl][it * 16 + 4 * hi];

    f32x16 s = __builtin_amdgcn_mfma_f32_32x32x16_bf16(as_bf16x8(ka), qfrag,
                                                       cmb, 0, 0, 0);
    float p[16];
#pragma unroll
    for (int i = 0; i < 16; ++i) p[i] = __builtin_amdgcn_exp2f(s[i]);
    const unsigned c01 = cvt_pk_bf16(p[0], p[1]);
    const unsigned c23 = cvt_pk_bf16(p[2], p[3]);
    const unsigned c45 = cvt_pk_bf16(p[4], p[5]);
    const unsigned c67 = cvt_pk_bf16(p[6], p[7]);
    const unsigned c89 = cvt_pk_bf16(p[8], p[9]);
    const unsigned cAB = cvt_pk_bf16(p[10], p[11]);
    const unsigned cCD = cvt_pk_bf16(p[12], p[13]);
    const unsigned cEF = cvt_pk_bf16(p[14], p[15]);
    const u32x2 r0 = __builtin_amdgcn_permlane32_swap(c01, c45, false, false);
    const u32x2 r1 = __builtin_amdgcn_permlane32_swap(c23, c67, false, false);
    const u32x2 r2 = __builtin_amdgcn_permlane32_swap(c89, cCD, false, false);
    const u32x2 r3 = __builtin_amdgcn_permlane32_swap(cAB, cEF, false, false);
    const uint4 pb0 = make_uint4(r0[0], r1[0], r0[1], r1[1]);
    const uint4 pb1 = make_uint4(r2[0], r3[0], r2[1], r3[1]);
    oacc = __builtin_amdgcn_mfma_f32_32x32x16_bf16(as_bf16x8(vv),
                                                   as_bf16x8(pb0), oacc, 0, 0, 0);
    const uint4 vv2 = *(const uint4*)&Vl[dcl][it * 16 + 8 + 4 * hi];
    oacc = __builtin_amdgcn_mfma_f32_32x32x16_bf16(as_bf16x8(vv2),
                                                   as_bf16x8(pb1), oacc, 0, 0, 0);
  }

  // ---- epilogue (proven): hi=0 regs0-3 = d0..3; hi=1 = d4,d5,l,junk
  const float a4 = __shfl_xor(oacc[0], 32);
  const float a5 = __shfl_xor(oacc[1], 32);
  const float ll = __shfl_xor(oacc[2], 32);
  if (hi == 0) {
    float* __restrict__ Pr = P + (((size_t)(bh * KSPLIT + ks)) * TT + q) * 8;
    ((float4*)Pr)[0] = make_float4(ll, oacc[0], oacc[1], oacc[2]);
    ((float4*)Pr)[1] = make_float4(oacc[3], a4, a5, 0.f);
  }
}

// ---------- kernel 3: combine partials + output projection (proven) --------
__global__ __launch_bounds__(256, 4) void combine_outproj_kernel(
    const float* __restrict__ P, const float* __restrict__ Wo,
    float* __restrict__ out) {
  __shared__ float wsh[DM * DM];
  __shared__ float o[32][25];
  for (int i = threadIdx.x; i < DM * DM; i += 256) wsh[i] = Wo[i];
  const int r0 = blockIdx.x * 32;
  {
    const int unit = threadIdx.x >> 1, e = threadIdx.x & 1;
    const int rl = unit >> 2, h = unit & 3;
    const int r = r0 + rl, b = r >> 10, t = r & (TT - 1);
    const int bh = b * NH + h;
    const float4* __restrict__ pp =
        (const float4*)(P + (((size_t)(bh * KSPLIT + e)) * TT + t) * 8);
    float4 x0 = pp[0], x1 = pp[1];
    float l = x0.x, a0 = x0.y, a1 = x0.z, a2 = x0.w;
    float a3 = x1.x, a4 = x1.y, a5 = x1.z;
    l += __shfl_xor(l, 1);
    a0 += __shfl_xor(a0, 1);
    a1 += __shfl_xor(a1, 1);
    a2 += __shfl_xor(a2, 1);
    a3 += __shfl_xor(a3, 1);
    a4 += __shfl_xor(a4, 1);
    a5 += __shfl_xor(a5, 1);
    if (e == 0) {
      const float inv = 1.f / l;
      o[rl][h * HD + 0] = a0 * inv;
      o[rl][h * HD + 1] = a1 * inv;
      o[rl][h * HD + 2] = a2 * inv;
      o[rl][h * HD + 3] = a3 * inv;
      o[rl][h * HD + 4] = a4 * inv;
      o[rl][h * HD + 5] = a5 * inv;
    }
  }
  __syncthreads();
  const int rl = threadIdx.x >> 3, u = threadIdx.x & 7;
  const int r = r0 + rl;
  float x[DM];
#pragma unroll
  for (int c = 0; c < DM; ++c) x[c] = o[rl][c];
#pragma unroll
  for (int jj = 0; jj < 3; ++jj) {
    const int j = u * 3 + jj;
    float a = 0.f;
#pragma unroll
    for (int c = 0; c < DM; ++c) a = fmaf(x[c], wsh[j * DM + c], a);
    out[(size_t)r * DM + j] = a;
  }
}

// ---------- launch ----------
extern "C" void kernel_launch(void* const* d_in, const int* in_sizes, int n_in,
                              void* d_out, int out_size, void* d_ws, size_t ws_size,
                              hipStream_t stream) {
  const float* X = (const float*)d_in[0];
  const float* Xen = (const float*)d_in[1];
  // d_in[2] = I_m : dead in the reference (masked_fill result discarded)
  const float* Wq = (const float*)d_in[3];
  const float* Wk = (const float*)d_in[4];
  const float* Wv = (const float*)d_in[5];
  const float* Wo = (const float*)d_in[6];

  char* ws = (char*)d_ws;
  float* P = (float*)ws;                               // 4 MB
  uint4* Kg = (uint4*)(ws + 4u * 1024 * 1024);         // 64*2*512*16B = 1 MB
  unsigned* Vt = (unsigned*)(ws + 5u * 1024 * 1024);   // 768*256*4B = 768 KB

  kvproj_kernel<<<1024, 256, 0, stream>>>(Xen, Wk, Wv, Kg, Vt);
  fused_attn32_kernel<<<NB * NH * 8 * KSPLIT, 256, 0, stream>>>(X, Wq, Kg, Vt,
                                                                P);
  combine_outproj_kernel<<<NB * TT / 32, 256, 0, stream>>>(P, Wo,
                                                           (float*)d_out);
}

// Round 20
// 24.080 us; speedup vs baseline: 1.2137x; 1.2137x over previous
//
#include <hip/hip_runtime.h>
#include <hip/hip_bf16.h>

#define NB 16      // batch
#define TT 1024    // Tq == Tk
#define NH 4       // heads
#define HD 6       // head dim
#define DM 24      // model dim

// (1/sqrt(6)) * log2(e) -- folded into Q so scores are in exp2 domain
#define QSC 0.5889785f
// fixed conservative bias (log2 domain); softmax invariant; p <= 1, no overflow
#define MBIAS 32.0f

typedef float v2f __attribute__((ext_vector_type(2)));
typedef short bf16x8 __attribute__((ext_vector_type(8)));    // MFMA A/B frag
typedef float f32x16 __attribute__((ext_vector_type(16)));   // MFMA 32x32 C/D
typedef unsigned u32x2 __attribute__((ext_vector_type(2)));

__device__ __forceinline__ unsigned cvt_pk_bf16(float lo, float hi) {
  unsigned r;
  asm("v_cvt_pk_bf16_f32 %0, %1, %2" : "=v"(r) : "v"(lo), "v"(hi));
  return r;
}

__device__ __forceinline__ bf16x8 as_bf16x8(uint4 u) {
  union { uint4 u; bf16x8 b; } c;
  c.u = u;
  return c.b;
}

// packed dot of one 24-float row with a uniform (SGPR) weight row
__device__ __forceinline__ float dot24(const float4* r,
                                       const float* __restrict__ w) {
  v2f a = {0.f, 0.f};
#pragma unroll
  for (int i = 0; i < 6; ++i) {
    v2f xp, wp;
    xp.x = r[i].x; xp.y = r[i].y;
    wp.x = w[4 * i + 0]; wp.y = w[4 * i + 1];
    a = __builtin_elementwise_fma(xp, wp, a);
    xp.x = r[i].z; xp.y = r[i].w;
    wp.x = w[4 * i + 2]; wp.y = w[4 * i + 3];
    a = __builtin_elementwise_fma(xp, wp, a);
  }
  return a.x + a.y;
}

// ---------------- kernel 1: fused KV-proj (to LDS) + 32x32 MFMA attention --
// R13 structure (25.04us proven; R16-R19 prologue alternatives all failed).
// Round-20 deltas (schedule-only, bit-identical math):
//  (1) 1-deep LDS prefetch in the main loop (R6-proven pattern);
//  (2) s_setprio(1) around the compute cluster (T5; blocks on a CU are at
//      different phases -> stager-vs-looper wave diversity);
//  (3) ka read unconditional (hi=1 A-half multiplies only zeros in qfrag --
//      R10-proven garbage-x-0 trick; drops a cndmask chain).
#define KSPLIT 2
#define KPB (TT / KSPLIT)  // 512 keys/block
#define QB 128             // queries/block
#define ITERS (KPB / 32)   // 16

__global__ __launch_bounds__(256, 4) void fused_attn32_kernel(
    const float* __restrict__ X, const float* __restrict__ Xen,
    const float* __restrict__ Wq, const float* __restrict__ Wk,
    const float* __restrict__ Wv, float* __restrict__ P) {
  __shared__ __align__(16) uint4 Kl[KPB];       // 8192 B
  __shared__ __align__(16) unsigned Vl[7][264]; // 7392 B

  const int ks = blockIdx.x & 1;
  const int tile = (blockIdx.x >> 1) & 7;
  const int bh = blockIdx.x >> 4;
  const int b = bh >> 2, h = bh & 3;
  const int t = threadIdx.x;

  // uniform weight slices (SGPR s_load path, R8-proven)
  const float* __restrict__ wqh = Wq + h * HD * DM;
  const float* __restrict__ wkh = Wk + h * HD * DM;
  const float* __restrict__ wvh = Wv + h * HD * DM;

  // ---- phase 1: project this thread's key pair (2t, 2t+1) into LDS
  {
    const float4* __restrict__ xe =
        (const float4*)(Xen + ((size_t)b * TT + ks * KPB + 2 * t) * DM);
    float4 xr[12];
#pragma unroll
    for (int i = 0; i < 12; ++i) xr[i] = xe[i];  // rows 2t (0-5), 2t+1 (6-11)
    float kA[HD], kB[HD];
#pragma unroll
    for (int d = 0; d < HD; ++d) {
      kA[d] = dot24(xr + 0, wkh + d * DM);
      kB[d] = dot24(xr + 6, wkh + d * DM);
    }
    Kl[2 * t] = make_uint4(cvt_pk_bf16(kA[0], kA[1]), cvt_pk_bf16(kA[2], kA[3]),
                           cvt_pk_bf16(kA[4], kA[5]), 0u);
    Kl[2 * t + 1] =
        make_uint4(cvt_pk_bf16(kB[0], kB[1]), cvt_pk_bf16(kB[2], kB[3]),
                   cvt_pk_bf16(kB[4], kB[5]), 0u);
#pragma unroll
    for (int d = 0; d < HD; ++d) {
      const float vA = dot24(xr + 0, wvh + d * DM);
      const float vB = dot24(xr + 6, wvh + d * DM);
      Vl[d][t] = cvt_pk_bf16(vA, vB);
    }
    Vl[6][t] = 0x3F803F80u;  // ones row -> l accumulates via MFMA row 6
  }

  // ---- phase 2: Q projection -> B-frag (hi==0 lanes real, hi==1 zero)
  const int lane = t & 63;
  const int w = t >> 6;
  const int hi = lane >> 5;
  const int qc = lane & 31;
  const int q = tile * QB + w * 32 + qc;
  uint4 uq = make_uint4(0u, 0u, 0u, 0u);
  if (hi == 0) {
    const float4* __restrict__ xq =
        (const float4*)(X + ((size_t)b * TT + q) * DM);
    float4 xr[6];
#pragma unroll
    for (int i = 0; i < 6; ++i) xr[i] = xq[i];
    float qv[HD];
#pragma unroll
    for (int d = 0; d < HD; ++d) qv[d] = dot24(xr, wqh + d * DM) * QSC;
    uq = make_uint4(cvt_pk_bf16(qv[0], qv[1]), cvt_pk_bf16(qv[2], qv[3]),
                    cvt_pk_bf16(qv[4], qv[5]), 0u);
  }
  const bf16x8 qfrag = as_bf16x8(uq);

  __syncthreads();  // LDS K/V ready

  f32x16 cmb, oacc;
#pragma unroll
  for (int i = 0; i < 16; ++i) { cmb[i] = -MBIAS; oacc[i] = 0.f; }

  const int dcl = (qc < 7) ? qc : 6;

  // compute one 32-key iteration (R11/R13-proven math, verbatim)
  auto compute = [&](uint4 ka, uint4 vv, uint4 vv2) {
    f32x16 s = __builtin_amdgcn_mfma_f32_32x32x16_bf16(as_bf16x8(ka), qfrag,
                                                       cmb, 0, 0, 0);
    float p[16];
#pragma unroll
    for (int i = 0; i < 16; ++i) p[i] = __builtin_amdgcn_exp2f(s[i]);
    const unsigned c01 = cvt_pk_bf16(p[0], p[1]);
    const unsigned c23 = cvt_pk_bf16(p[2], p[3]);
    const unsigned c45 = cvt_pk_bf16(p[4], p[5]);
    const unsigned c67 = cvt_pk_bf16(p[6], p[7]);
    const unsigned c89 = cvt_pk_bf16(p[8], p[9]);
    const unsigned cAB = cvt_pk_bf16(p[10], p[11]);
    const unsigned cCD = cvt_pk_bf16(p[12], p[13]);
    const unsigned cEF = cvt_pk_bf16(p[14], p[15]);
    const u32x2 r0 = __builtin_amdgcn_permlane32_swap(c01, c45, false, false);
    const u32x2 r1 = __builtin_amdgcn_permlane32_swap(c23, c67, false, false);
    const u32x2 r2 = __builtin_amdgcn_permlane32_swap(c89, cCD, false, false);
    const u32x2 r3 = __builtin_amdgcn_permlane32_swap(cAB, cEF, false, false);
    const uint4 pb0 = make_uint4(r0[0], r1[0], r0[1], r1[1]);
    const uint4 pb1 = make_uint4(r2[0], r3[0], r2[1], r3[1]);
    oacc = __builtin_amdgcn_mfma_f32_32x32x16_bf16(as_bf16x8(vv),
                                                   as_bf16x8(pb0), oacc, 0, 0, 0);
    oacc = __builtin_amdgcn_mfma_f32_32x32x16_bf16(as_bf16x8(vv2),
                                                   as_bf16x8(pb1), oacc, 0, 0, 0);
  };

  // ---- main loop with 1-deep prefetch (ka read on ALL lanes: hi=1 half
  //      multiplies only zeros in qfrag -> any finite value is safe)
  uint4 ka = Kl[qc];
  uint4 vv = *(const uint4*)&Vl[dcl][4 * hi];
  uint4 vv2 = *(const uint4*)&Vl[dcl][8 + 4 * hi];
#pragma unroll 2
  for (int it = 0; it < ITERS - 1; ++it) {
    const uint4 nka = Kl[(it + 1) * 32 + qc];
    const uint4 nvv = *(const uint4*)&Vl[dcl][(it + 1) * 16 + 4 * hi];
    const uint4 nvv2 = *(const uint4*)&Vl[dcl][(it + 1) * 16 + 8 + 4 * hi];
    __builtin_amdgcn_s_setprio(1);
    compute(ka, vv, vv2);
    __builtin_amdgcn_s_setprio(0);
    ka = nka; vv = nvv; vv2 = nvv2;
  }
  __builtin_amdgcn_s_setprio(1);
  compute(ka, vv, vv2);
  __builtin_amdgcn_s_setprio(0);

  // ---- epilogue (proven): hi=0 regs0-3 = d0..3; hi=1 = d4,d5,l,junk
  const float a4 = __shfl_xor(oacc[0], 32);
  const float a5 = __shfl_xor(oacc[1], 32);
  const float ll = __shfl_xor(oacc[2], 32);
  if (hi == 0) {
    float* __restrict__ Pr = P + (((size_t)(bh * KSPLIT + ks)) * TT + q) * 8;
    ((float4*)Pr)[0] = make_float4(ll, oacc[0], oacc[1], oacc[2]);
    ((float4*)Pr)[1] = make_float4(oacc[3], a4, a5, 0.f);
  }
}

// ---------- kernel 2: combine partials + output projection (proven) --------
__global__ __launch_bounds__(256, 4) void combine_outproj_kernel(
    const float* __restrict__ P, const float* __restrict__ Wo,
    float* __restrict__ out) {
  __shared__ float wsh[DM * DM];
  __shared__ float o[32][25];
  for (int i = threadIdx.x; i < DM * DM; i += 256) wsh[i] = Wo[i];
  const int r0 = blockIdx.x * 32;
  {
    const int unit = threadIdx.x >> 1, e = threadIdx.x & 1;
    const int rl = unit >> 2, h = unit & 3;
    const int r = r0 + rl, b = r >> 10, t = r & (TT - 1);
    const int bh = b * NH + h;
    const float4* __restrict__ pp =
        (const float4*)(P + (((size_t)(bh * KSPLIT + e)) * TT + t) * 8);
    float4 x0 = pp[0], x1 = pp[1];
    float l = x0.x, a0 = x0.y, a1 = x0.z, a2 = x0.w;
    float a3 = x1.x, a4 = x1.y, a5 = x1.z;
    l += __shfl_xor(l, 1);
    a0 += __shfl_xor(a0, 1);
    a1 += __shfl_xor(a1, 1);
    a2 += __shfl_xor(a2, 1);
    a3 += __shfl_xor(a3, 1);
    a4 += __shfl_xor(a4, 1);
    a5 += __shfl_xor(a5, 1);
    if (e == 0) {
      const float inv = 1.f / l;
      o[rl][h * HD + 0] = a0 * inv;
      o[rl][h * HD + 1] = a1 * inv;
      o[rl][h * HD + 2] = a2 * inv;
      o[rl][h * HD + 3] = a3 * inv;
      o[rl][h * HD + 4] = a4 * inv;
      o[rl][h * HD + 5] = a5 * inv;
    }
  }
  __syncthreads();
  const int rl = threadIdx.x >> 3, u = threadIdx.x & 7;
  const int r = r0 + rl;
  float x[DM];
#pragma unroll
  for (int c = 0; c < DM; ++c) x[c] = o[rl][c];
#pragma unroll
  for (int jj = 0; jj < 3; ++jj) {
    const int j = u * 3 + jj;
    float a = 0.f;
#pragma unroll
    for (int c = 0; c < DM; ++c) a = fmaf(x[c], wsh[j * DM + c], a);
    out[(size_t)r * DM + j] = a;
  }
}

// ---------- launch ----------
extern "C" void kernel_launch(void* const* d_in, const int* in_sizes, int n_in,
                              void* d_out, int out_size, void* d_ws, size_t ws_size,
                              hipStream_t stream) {
  const float* X = (const float*)d_in[0];
  const float* Xen = (const float*)d_in[1];
  // d_in[2] = I_m : dead in the reference (masked_fill result discarded)
  const float* Wq = (const float*)d_in[3];
  const float* Wk = (const float*)d_in[4];
  const float* Wv = (const float*)d_in[5];
  const float* Wo = (const float*)d_in[6];

  float* P = (float*)d_ws;  // [64 bh][2 ks][1024 q][8] = 4 MB

  fused_attn32_kernel<<<NB * NH * 8 * KSPLIT, 256, 0, stream>>>(X, Xen, Wq,
                                                                Wk, Wv, P);
  combine_outproj_kernel<<<NB * TT / 32, 256, 0, stream>>>(P, Wo,
                                                           (float*)d_out);
}